// Round 8
// baseline (57.251 us; speedup 1.0000x reference)
//
#include <hip/hip_runtime.h>

typedef unsigned short u16;
typedef unsigned int u32;
typedef __bf16 bf16x8 __attribute__((ext_vector_type(8)));
typedef float f32x4 __attribute__((ext_vector_type(4)));
typedef u32 u32x4 __attribute__((ext_vector_type(4)));

#define AS1 __attribute__((address_space(1)))
#define AS3 __attribute__((address_space(3)))

// kT[t][c][r]  (fallback kernel layout)
__device__ __align__(16) u16 g_kT[27 * 64 * 64];
// kTr[((t*2+nh)*2+nt)*2+kb][lane][j] : per-lane-ordered repack -> every
// B-load is one fully-contiguous 1KB wave read (8 fully-used cachelines).
__device__ __align__(16) u16 g_kTr[27 * 8 * 512];

__device__ __forceinline__ u16 f2bf(float f) {
    unsigned int u = __float_as_uint(f);
    u += 0x7FFFu + ((u >> 16) & 1u);   // RNE
    return (u16)(u >> 16);
}

__device__ __forceinline__ u32 pack_bf(float a, float b) {
    u32 ua = __float_as_uint(a) + 0x8000u;
    u32 ub = __float_as_uint(b) + 0x8000u;
    return __builtin_amdgcn_perm(ub, ua, 0x07060302u);
}

// ---------------------------------------------------------------------------
// Build kT + repacked kTr (+ fold self-connection into center tap).
// ---------------------------------------------------------------------------
__global__ __launch_bounds__(64) void build_k(
    const float* __restrict__ Wsc0, const float* __restrict__ Wsc1,
    const float* __restrict__ w1, const float* __restrict__ w2,
    const float* __restrict__ w3, const float* __restrict__ w4)
{
    const int t = blockIdx.x;
    const int c = threadIdx.x;
    const int dx = t / 9 - 1, dy = (t / 3) % 3 - 1, dz = t % 3 - 1;
    const float d = sqrtf((float)(dx * dx + dy * dy + dz * dz));
    const float step = 1.5f / 9.0f;
    float emb[8];
#pragma unroll
    for (int k = 0; k < 8; ++k) {
        float diff = (d - (float)(k + 1) * step) / step;
        float q = diff * diff;
        emb[k] = (q < 1.0f) ? 1.14136f * expf(2.0f - 2.0f / (1.0f - q)) : 0.0f;
    }
    const float dn = fmaxf(d, 1e-12f);
    const float s3 = 1.7320508075688772f;
    const float sh1[3] = { s3 * (float)dx / dn, s3 * (float)dy / dn, s3 * (float)dz / dn };
    const float alpha  = 0.17677669529663687f;
    const float alpha3 = alpha * 0.57735026918962576f;

    u16* outp = &g_kT[(t * 64 + c) * 64];
    const int base2 = ((t * 2 + (c >> 5)) * 2 + ((c >> 4) & 1)) * 2;
    const int l15c  = c & 15;
    auto put = [&](int r, float v) {
        u16 h = f2bf(v);
        outp[r] = h;
        g_kTr[(base2 + (r >> 5)) * 512 + (((r >> 3) & 3) * 16 + l15c) * 8 + (r & 7)] = h;
    };

    if (c < 16) {
        const int o = c;
#pragma unroll
        for (int i = 0; i < 16; ++i) {
            float W1 = 0.f, W4 = 0.f;
#pragma unroll
            for (int k = 0; k < 8; ++k) {
                W1 += emb[k] * w1[k * 256 + i * 16 + o];
                W4 += emb[k] * w4[k * 256 + i * 16 + o];
            }
            W1 *= (1.0f / 27.0f); W4 *= (1.0f / 27.0f);
            float v0 = alpha * W1;
            if (t == 13) v0 += 0.25f * Wsc0[i * 16 + o];
            put(i, v0);
            const float base = alpha3 * W4;
#pragma unroll
            for (int m = 0; m < 3; ++m) put(16 + 3 * i + m, base * sh1[m]);
        }
    } else {
        const int o = (c - 16) / 3, nc = (c - 16) % 3;
#pragma unroll
        for (int i = 0; i < 16; ++i) {
            float W2 = 0.f, W3 = 0.f;
#pragma unroll
            for (int k = 0; k < 8; ++k) {
                W2 += emb[k] * w2[k * 256 + i * 16 + o];
                W3 += emb[k] * w3[k * 256 + i * 16 + o];
            }
            W2 *= (1.0f / 27.0f); W3 *= (1.0f / 27.0f);
            put(i, alpha * W2 * sh1[nc]);
#pragma unroll
            for (int m = 0; m < 3; ++m) {
                float v = (m == nc) ? alpha * W3 : 0.0f;
                if (t == 13 && m == nc) v += 0.25f * Wsc1[i * 16 + o];
                put(16 + 3 * i + m, v);
            }
        }
    }
}

// ---------------------------------------------------------------------------
// Pre-convert x (fp32) -> xb (bf16) + 4KB zero page.
// ---------------------------------------------------------------------------
__global__ __launch_bounds__(256) void cvt_x(
    const float* __restrict__ x, u16* __restrict__ xb, u32* __restrict__ zp)
{
    const int tid = threadIdx.x;
    if (blockIdx.x == 0) {
        u32x4 z = {0u, 0u, 0u, 0u};
        *reinterpret_cast<u32x4*>(zp + tid * 4) = z;
    }
    const size_t base = ((size_t)blockIdx.x * 256 + tid) * 8;
    const float4* s = reinterpret_cast<const float4*>(x + base);
    float4 v0 = s[0], v1 = s[1];
    u32x4 p;
    p[0] = pack_bf(v0.x, v0.y); p[1] = pack_bf(v0.z, v0.w);
    p[2] = pack_bf(v1.x, v1.y); p[3] = pack_bf(v1.z, v1.w);
    *reinterpret_cast<u32x4*>(xb + base) = p;
}

// ---------------------------------------------------------------------------
// v5: block = (b, X, 8y), 256 thr / 4 waves, 1 block/CU (128KB dynamic LDS).
// Wave (yh, nh): M = 4y x 32z = 128 positions, N = 32 ch -> per-wave B L2
// traffic halved again vs v4 (0.6 MB/CU, under the MFMA shadow).
// ---------------------------------------------------------------------------
#define NROWS5 1020   // 3 dx * 10 y * 34 z
#define NCHUNK5 128   // 1024 rows staged (last 4 rows = zero pad)
#define LDSB   (NCHUNK5 * 1024)

#define ISSUE_B(s, t) \
  { const char* _p = bTr + (t) * 8192; \
    asm volatile("global_load_dwordx4 %0, %4, off\n\t" \
                 "global_load_dwordx4 %1, %4, off offset:1024\n\t" \
                 "global_load_dwordx4 %2, %4, off offset:2048\n\t" \
                 "global_load_dwordx4 %3, %4, off offset:3072" \
                 : "=&v"(B##s##0), "=&v"(B##s##1), "=&v"(B##s##2), "=&v"(B##s##3) \
                 : "v"(_p)); }

// r = rbase + RCC ; granule XOR-swizzle matches staging layout; kb -> ^64.
#define LOADA2(s, i0, i1, RCC) { \
  const int _r  = rbase + (RCC); \
  const int _o0 = _r * 128 + ((kg ^ (_r & 7)) << 4); \
  A##s##_##i0 = *reinterpret_cast<const bf16x8*>(abase + _o0); \
  A##s##_##i1 = *reinterpret_cast<const bf16x8*>(abase + (_o0 ^ 64)); }

// row const: dx*340 + (dy+YY)*34 + dz + MT*16   (T literal -> folded)
#define RCC5(T, YY, MT) ((((T)/9)*340 + ((((T)/3)%3) + (YY))*34 + ((T)%3) + (MT)*16))

#define LOAD_A16(s, T) \
  LOADA2(s, 0,  1,  RCC5(T,0,0)) \
  LOADA2(s, 2,  3,  RCC5(T,0,1)) \
  LOADA2(s, 4,  5,  RCC5(T,1,0)) \
  LOADA2(s, 6,  7,  RCC5(T,1,1)) \
  LOADA2(s, 8,  9,  RCC5(T,2,0)) \
  LOADA2(s, 10, 11, RCC5(T,2,1)) \
  LOADA2(s, 12, 13, RCC5(T,3,0)) \
  LOADA2(s, 14, 15, RCC5(T,3,1))

#define WAITV(N) \
  asm volatile("s_waitcnt vmcnt(" #N ")" ::: "memory"); \
  __builtin_amdgcn_sched_barrier(0);

#define BC(x) __builtin_bit_cast(bf16x8, x)
#define MF(b_, a_, c_) __builtin_amdgcn_mfma_f32_16x16x32_bf16(BC(b_), a_, c_, 0, 0, 0)

// 32 MFMAs: acc{yy}{mt}{nt} += B(kb,nt) x A(yy,mt,kb);  B idx = nt*2+kb.
#define MFMA32(bs, as) \
  acc000 = MF(B##bs##0, A##as##_0,  acc000);  acc001 = MF(B##bs##2, A##as##_0,  acc001); \
  acc010 = MF(B##bs##0, A##as##_2,  acc010);  acc011 = MF(B##bs##2, A##as##_2,  acc011); \
  acc100 = MF(B##bs##0, A##as##_4,  acc100);  acc101 = MF(B##bs##2, A##as##_4,  acc101); \
  acc110 = MF(B##bs##0, A##as##_6,  acc110);  acc111 = MF(B##bs##2, A##as##_6,  acc111); \
  acc200 = MF(B##bs##0, A##as##_8,  acc200);  acc201 = MF(B##bs##2, A##as##_8,  acc201); \
  acc210 = MF(B##bs##0, A##as##_10, acc210);  acc211 = MF(B##bs##2, A##as##_10, acc211); \
  acc300 = MF(B##bs##0, A##as##_12, acc300);  acc301 = MF(B##bs##2, A##as##_12, acc301); \
  acc310 = MF(B##bs##0, A##as##_14, acc310);  acc311 = MF(B##bs##2, A##as##_14, acc311); \
  acc000 = MF(B##bs##1, A##as##_1,  acc000);  acc001 = MF(B##bs##3, A##as##_1,  acc001); \
  acc010 = MF(B##bs##1, A##as##_3,  acc010);  acc011 = MF(B##bs##3, A##as##_3,  acc011); \
  acc100 = MF(B##bs##1, A##as##_5,  acc100);  acc101 = MF(B##bs##3, A##as##_5,  acc101); \
  acc110 = MF(B##bs##1, A##as##_7,  acc110);  acc111 = MF(B##bs##3, A##as##_7,  acc111); \
  acc200 = MF(B##bs##1, A##as##_9,  acc200);  acc201 = MF(B##bs##3, A##as##_9,  acc201); \
  acc210 = MF(B##bs##1, A##as##_11, acc210);  acc211 = MF(B##bs##3, A##as##_11, acc211); \
  acc300 = MF(B##bs##1, A##as##_13, acc300);  acc301 = MF(B##bs##3, A##as##_13, acc301); \
  acc310 = MF(B##bs##1, A##as##_15, acc310);  acc311 = MF(B##bs##3, A##as##_15, acc311);

__global__ __launch_bounds__(256, 1) void conv_mfma5(
    const u16* __restrict__ xb, const u32* __restrict__ zp,
    float* __restrict__ out)
{
    extern __shared__ u16 xt[];   // LDSB bytes

    const int bid0 = blockIdx.x;
    const int bid  = (bid0 & 7) * 64 + (bid0 >> 3);    // XCD-contiguous panels
    const int b    = bid >> 7;
    const int X    = (bid >> 2) & 31;
    const int y0   = (bid & 3) << 3;
    const int tid  = threadIdx.x;
    const int wv   = tid >> 6;
    const int lane = tid & 63;
    const int l15  = lane & 15;
    const int kg   = lane >> 4;
    const int yh   = wv >> 1;
    const int nh   = wv & 1;

    const char* bTr = (const char*)g_kTr + nh * 4096 + lane * 16;

    u32x4 B00, B01, B02, B03, B10, B11, B12, B13, B20, B21, B22, B23;
    bf16x8 A0_0, A0_1, A0_2,  A0_3,  A0_4,  A0_5,  A0_6,  A0_7,
           A0_8, A0_9, A0_10, A0_11, A0_12, A0_13, A0_14, A0_15;
    bf16x8 A1_0, A1_1, A1_2,  A1_3,  A1_4,  A1_5,  A1_6,  A1_7,
           A1_8, A1_9, A1_10, A1_11, A1_12, A1_13, A1_14, A1_15;

    // prologue B: taps 1, 3 in flight before staging; drained with it
    ISSUE_B(0, 1)
    ISSUE_B(1, 3)

    // ---- staging: 128 chunks x 1KB; rows (dx*10 + yi)*34 + zid, XOR-swizzled ----
    {
        const int rloc = lane >> 3;
        const int swz  = (lane & 7) ^ rloc;
#pragma unroll
        for (int i = 0; i < 32; ++i) {
            const int c = wv * 32 + i;
            const int row = c * 8 + rloc;
            const int dxx = row / 340;
            const int rem = row - dxx * 340;
            const int yi  = rem / 34;
            const int zid = rem - yi * 34;
            const int xin = X + dxx - 1;
            const int yin = y0 + yi - 1;
            const int zin = zid - 1;
            const bool inb = (row < NROWS5) & ((unsigned)xin < 32u)
                           & ((unsigned)yin < 32u) & ((unsigned)zin < 32u);
            const u16* src = inb
                ? xb + ((size_t)(((b * 32 + xin) * 32 + yin) * 32 + zin) * 64 + swz * 8)
                : (const u16*)zp;
            __builtin_amdgcn_global_load_lds((const AS1 u32*)src,
                                             (AS3 u32*)&xt[c * 512], 16, 0, 0);
        }
    }
    asm volatile("s_waitcnt vmcnt(0)" ::: "memory");
    __syncthreads();

    const char* abase = reinterpret_cast<const char*>(xt);
    const int rbase = yh * 136 + l15;    // yh*4 rows of y, *34

    const f32x4 z4 = {0.f, 0.f, 0.f, 0.f};
    f32x4 acc000 = z4, acc001 = z4, acc010 = z4, acc011 = z4;
    f32x4 acc100 = z4, acc101 = z4, acc110 = z4, acc111 = z4;
    f32x4 acc200 = z4, acc201 = z4, acc210 = z4, acc211 = z4;
    f32x4 acc300 = z4, acc301 = z4, acc310 = z4, acc311 = z4;

    LOAD_A16(0, 1)

    // taps {1,3,4,5,7,9,10,11,12,13,14,15,16,17,19,21,22,23,25}
    ISSUE_B(2, 4)   LOAD_A16(1, 3)   WAITV(8)  MFMA32(0, 0)   // t=1
    ISSUE_B(0, 5)   LOAD_A16(0, 4)   WAITV(8)  MFMA32(1, 1)   // t=3
    ISSUE_B(1, 7)   LOAD_A16(1, 5)   WAITV(8)  MFMA32(2, 0)   // t=4
    ISSUE_B(2, 9)   LOAD_A16(0, 7)   WAITV(8)  MFMA32(0, 1)   // t=5
    ISSUE_B(0, 10)  LOAD_A16(1, 9)   WAITV(8)  MFMA32(1, 0)   // t=7
    ISSUE_B(1, 11)  LOAD_A16(0, 10)  WAITV(8)  MFMA32(2, 1)   // t=9
    ISSUE_B(2, 12)  LOAD_A16(1, 11)  WAITV(8)  MFMA32(0, 0)   // t=10
    ISSUE_B(0, 13)  LOAD_A16(0, 12)  WAITV(8)  MFMA32(1, 1)   // t=11
    ISSUE_B(1, 14)  LOAD_A16(1, 13)  WAITV(8)  MFMA32(2, 0)   // t=12
    ISSUE_B(2, 15)  LOAD_A16(0, 14)  WAITV(8)  MFMA32(0, 1)   // t=13
    ISSUE_B(0, 16)  LOAD_A16(1, 15)  WAITV(8)  MFMA32(1, 0)   // t=14
    ISSUE_B(1, 17)  LOAD_A16(0, 16)  WAITV(8)  MFMA32(2, 1)   // t=15
    ISSUE_B(2, 19)  LOAD_A16(1, 17)  WAITV(8)  MFMA32(0, 0)   // t=16
    ISSUE_B(0, 21)  LOAD_A16(0, 19)  WAITV(8)  MFMA32(1, 1)   // t=17
    ISSUE_B(1, 22)  LOAD_A16(1, 21)  WAITV(8)  MFMA32(2, 0)   // t=19
    ISSUE_B(2, 23)  LOAD_A16(0, 22)  WAITV(8)  MFMA32(0, 1)   // t=21
    ISSUE_B(0, 25)  LOAD_A16(1, 23)  WAITV(8)  MFMA32(1, 0)   // t=22
                    LOAD_A16(0, 25)  WAITV(4)  MFMA32(2, 1)   // t=23
                                     WAITV(0)  MFMA32(0, 0)   // t=25

    // ---- epilogue: y = y0+yh*4+yy, z = mt*16+l15, ch = nh*32+nt*16+kg*4 ----
    float* obase = out + (((size_t)(b * 32 + X) * 32 + (y0 + yh * 4)) * 32) * 64
                 + nh * 32 + kg * 4;
    *reinterpret_cast<f32x4*>(obase + l15 * 64)                    = acc000;
    *reinterpret_cast<f32x4*>(obase + l15 * 64 + 16)               = acc001;
    *reinterpret_cast<f32x4*>(obase + (16 + l15) * 64)             = acc010;
    *reinterpret_cast<f32x4*>(obase + (16 + l15) * 64 + 16)        = acc011;
    *reinterpret_cast<f32x4*>(obase + 2048 + l15 * 64)             = acc100;
    *reinterpret_cast<f32x4*>(obase + 2048 + l15 * 64 + 16)        = acc101;
    *reinterpret_cast<f32x4*>(obase + 2048 + (16 + l15) * 64)      = acc110;
    *reinterpret_cast<f32x4*>(obase + 2048 + (16 + l15) * 64 + 16) = acc111;
    *reinterpret_cast<f32x4*>(obase + 4096 + l15 * 64)             = acc200;
    *reinterpret_cast<f32x4*>(obase + 4096 + l15 * 64 + 16)        = acc201;
    *reinterpret_cast<f32x4*>(obase + 4096 + (16 + l15) * 64)      = acc210;
    *reinterpret_cast<f32x4*>(obase + 4096 + (16 + l15) * 64 + 16) = acc211;
    *reinterpret_cast<f32x4*>(obase + 6144 + l15 * 64)             = acc300;
    *reinterpret_cast<f32x4*>(obase + 6144 + l15 * 64 + 16)        = acc301;
    *reinterpret_cast<f32x4*>(obase + 6144 + (16 + l15) * 64)      = acc310;
    *reinterpret_cast<f32x4*>(obase + 6144 + (16 + l15) * 64 + 16) = acc311;
}

// ---------------------------------------------------------------------------
// Fallback (fp32 staging through VGPRs, old g_kT layout), if ws too small.
// ---------------------------------------------------------------------------
#define ZS 68
#define NROWS 408

__global__ __launch_bounds__(256, 2) void conv_mfma_fb(
    const float* __restrict__ x, float* __restrict__ out)
{
    __shared__ __align__(16) u16 xts[NROWS * ZS];
    const int bid0 = blockIdx.x;
    const int bid  = (bid0 & 7) * 256 + (bid0 >> 3);
    const int b   = bid >> 9;
    const int X   = (bid >> 4) & 31;
    const int y0  = (bid & 15) << 1;
    const int tid = threadIdx.x;

    {
        const int pr = tid >> 2;
        const int q  = tid & 3;
#pragma unroll
        for (int pass = 0; pass < 7; ++pass) {
            const int idx = pass * 64 + pr;
            if (idx < NROWS) {
                const int rid = idx / 34;
                const int zid = idx - rid * 34;
                const int xin = X + (rid >> 2) - 1;
                const int yin = y0 + (rid & 3) - 1;
                const int zin = zid - 1;
                u32x4 p0 = {0u,0u,0u,0u}, p1 = {0u,0u,0u,0u};
                if ((unsigned)xin < 32u && (unsigned)yin < 32u && (unsigned)zin < 32u) {
                    const float4* src = reinterpret_cast<const float4*>(
                        x + ((((b * 32 + xin) * 32 + yin) * 32 + zin) * 64 + q * 16));
                    float4 v0 = src[0], v1 = src[1], v2 = src[2], v3 = src[3];
                    p0[0] = pack_bf(v0.x, v0.y); p0[1] = pack_bf(v0.z, v0.w);
                    p0[2] = pack_bf(v1.x, v1.y); p0[3] = pack_bf(v1.z, v1.w);
                    p1[0] = pack_bf(v2.x, v2.y); p1[1] = pack_bf(v2.z, v2.w);
                    p1[2] = pack_bf(v3.x, v3.y); p1[3] = pack_bf(v3.z, v3.w);
                }
                u16* dst = &xts[idx * ZS + q * 16];
                *reinterpret_cast<u32x4*>(dst)     = p0;
                *reinterpret_cast<u32x4*>(dst + 8) = p1;
            }
        }
    }
    __syncthreads();

    const int w    = tid >> 6;
    const int lane = tid & 63;
    const int l15  = lane & 15;
    const int kg   = lane >> 4;
    const int mh   = w >> 1;
    const int nh   = w & 1;
    const int chb  = kg * 8;

    const u16* abase = &xts[l15 * ZS + chb];
    const u16* bbase = &g_kT[(nh * 32 + l15) * 64 + chb];

    const f32x4 z4 = {0.f, 0.f, 0.f, 0.f};
    f32x4 acc[2][2] = {{z4, z4}, {z4, z4}};

    constexpr int NT = 19;
    constexpr int TAPS[NT] = {1,3,4,5,7,9,10,11,12,13,14,15,16,17,19,21,22,23,25};

#pragma unroll
    for (int ti = 0; ti < NT; ++ti) {
        const int t = TAPS[ti];
        const int dxt = t / 9, dyt = (t / 3) % 3, dzt = t % 3;
        const int rid = dxt * 4 + mh + dyt;
        bf16x8 bfr[4], afr[4];
#pragma unroll
        for (int kb = 0; kb < 2; ++kb)
#pragma unroll
        for (int nt = 0; nt < 2; ++nt)
            bfr[kb*2+nt] = *reinterpret_cast<const bf16x8*>(
                bbase + (t * 64 + nt * 16) * 64 + kb * 32);
#pragma unroll
        for (int kb = 0; kb < 2; ++kb)
#pragma unroll
        for (int mt = 0; mt < 2; ++mt)
            afr[kb*2+mt] = *reinterpret_cast<const bf16x8*>(
                abase + (rid * 34 + dzt + mt * 16) * ZS + kb * 32);
#pragma unroll
        for (int kb = 0; kb < 2; ++kb)
#pragma unroll
        for (int mt = 0; mt < 2; ++mt)
#pragma unroll
        for (int nt = 0; nt < 2; ++nt)
            acc[mt][nt] = __builtin_amdgcn_mfma_f32_16x16x32_bf16(
                bfr[kb*2+nt], afr[kb*2+mt], acc[mt][nt], 0, 0, 0);
    }

    float* obase = out + (((b * 32 + X) * 32 + (y0 + mh)) * 32) * 64 + nh * 32 + kg * 4;
#pragma unroll
    for (int mt = 0; mt < 2; ++mt)
#pragma unroll
        for (int nt = 0; nt < 2; ++nt) {
            float4 v;
            v.x = acc[mt][nt][0]; v.y = acc[mt][nt][1];
            v.z = acc[mt][nt][2]; v.w = acc[mt][nt][3];
            *reinterpret_cast<float4*>(obase + (mt * 16 + l15) * 64 + nt * 16) = v;
        }
}

extern "C" void kernel_launch(void* const* d_in, const int* in_sizes, int n_in,
                              void* d_out, int out_size, void* d_ws, size_t ws_size,
                              hipStream_t stream)
{
    const float* x    = (const float*)d_in[0];
    const float* Wsc0 = (const float*)d_in[1];
    const float* Wsc1 = (const float*)d_in[2];
    const float* w1   = (const float*)d_in[3];
    const float* w2   = (const float*)d_in[4];
    const float* w3   = (const float*)d_in[5];
    const float* w4   = (const float*)d_in[6];
    float* out = (float*)d_out;

    build_k<<<dim3(27), dim3(64), 0, stream>>>(Wsc0, Wsc1, w1, w2, w3, w4);

    const size_t xb_bytes = (size_t)4 * 32 * 32 * 32 * 64 * 2;   // 16.8 MB
    if (ws_size >= 4096 + xb_bytes) {
        u32* zp = (u32*)d_ws;
        u16* xb = (u16*)((char*)d_ws + 4096);
        cvt_x<<<dim3(4096), dim3(256), 0, stream>>>(x, xb, zp);
        conv_mfma5<<<dim3(512), dim3(256), LDSB, stream>>>(xb, zp, out);
    } else {
        conv_mfma_fb<<<dim3(2048), dim3(256), 0, stream>>>(x, out);
    }
}

// Round 9
// 53.794 us; speedup vs baseline: 1.0643x; 1.0643x over previous
//
#include <hip/hip_runtime.h>

typedef unsigned short u16;
typedef unsigned int u32;
typedef __bf16 bf16x8 __attribute__((ext_vector_type(8)));
typedef float f32x4 __attribute__((ext_vector_type(4)));
typedef u32 u32x4 __attribute__((ext_vector_type(4)));

#define AS1 __attribute__((address_space(1)))
#define AS3 __attribute__((address_space(3)))

// kT[t][c][r]  (fallback kernel layout)
__device__ __align__(16) u16 g_kT[27 * 64 * 64];
// kTr[((t*2+nh)*2+nt)*2+kb][lane][j] : per-lane-ordered repack -> every
// B-load is one fully-contiguous 1KB wave read (8 fully-used cachelines).
__device__ __align__(16) u16 g_kTr[27 * 8 * 512];

__device__ __forceinline__ u16 f2bf(float f) {
    unsigned int u = __float_as_uint(f);
    u += 0x7FFFu + ((u >> 16) & 1u);   // RNE
    return (u16)(u >> 16);
}

__device__ __forceinline__ u32 pack_bf(float a, float b) {
    u32 ua = __float_as_uint(a) + 0x8000u;
    u32 ub = __float_as_uint(b) + 0x8000u;
    return __builtin_amdgcn_perm(ub, ua, 0x07060302u);
}

// ---------------------------------------------------------------------------
// prep: blocks 0..26 build kT/kTr (+ fold self-connection into center tap);
//       blocks 27.. convert x fp32 -> bf16 (+ zero page in block 27).
// ---------------------------------------------------------------------------
__global__ __launch_bounds__(256) void prep(
    const float* __restrict__ Wsc0, const float* __restrict__ Wsc1,
    const float* __restrict__ w1, const float* __restrict__ w2,
    const float* __restrict__ w3, const float* __restrict__ w4,
    const float* __restrict__ x, u16* __restrict__ xb, u32* __restrict__ zp)
{
    const int tid = threadIdx.x;
    if (blockIdx.x < 27) {
        if (tid >= 64) return;
        const int t = blockIdx.x;
        const int c = tid;
        const int dx = t / 9 - 1, dy = (t / 3) % 3 - 1, dz = t % 3 - 1;
        const float d = sqrtf((float)(dx * dx + dy * dy + dz * dz));
        const float step = 1.5f / 9.0f;
        float emb[8];
#pragma unroll
        for (int k = 0; k < 8; ++k) {
            float diff = (d - (float)(k + 1) * step) / step;
            float q = diff * diff;
            emb[k] = (q < 1.0f) ? 1.14136f * expf(2.0f - 2.0f / (1.0f - q)) : 0.0f;
        }
        const float dn = fmaxf(d, 1e-12f);
        const float s3 = 1.7320508075688772f;
        const float sh1[3] = { s3 * dx / dn, s3 * dy / dn, s3 * dz / dn };
        const float alpha  = 0.17677669529663687f;
        const float alpha3 = alpha * 0.57735026918962576f;

        u16* outp = &g_kT[(t * 64 + c) * 64];
        const int base2 = ((t * 2 + (c >> 5)) * 2 + ((c >> 4) & 1)) * 2;
        const int l15c  = c & 15;
        auto put = [&](int r, float v) {
            u16 h = f2bf(v);
            outp[r] = h;
            g_kTr[(base2 + (r >> 5)) * 512 + (((r >> 3) & 3) * 16 + l15c) * 8 + (r & 7)] = h;
        };

        if (c < 16) {
            const int o = c;
#pragma unroll
            for (int i = 0; i < 16; ++i) {
                float W1 = 0.f, W4 = 0.f;
#pragma unroll
                for (int k = 0; k < 8; ++k) {
                    W1 += emb[k] * w1[k * 256 + i * 16 + o];
                    W4 += emb[k] * w4[k * 256 + i * 16 + o];
                }
                W1 *= (1.0f / 27.0f); W4 *= (1.0f / 27.0f);
                float v0 = alpha * W1;
                if (t == 13) v0 += 0.25f * Wsc0[i * 16 + o];
                put(i, v0);
                const float base = alpha3 * W4;
#pragma unroll
                for (int m = 0; m < 3; ++m) put(16 + 3 * i + m, base * sh1[m]);
            }
        } else {
            const int o = (c - 16) / 3, nc = (c - 16) % 3;
#pragma unroll
            for (int i = 0; i < 16; ++i) {
                float W2 = 0.f, W3 = 0.f;
#pragma unroll
                for (int k = 0; k < 8; ++k) {
                    W2 += emb[k] * w2[k * 256 + i * 16 + o];
                    W3 += emb[k] * w3[k * 256 + i * 16 + o];
                }
                W2 *= (1.0f / 27.0f); W3 *= (1.0f / 27.0f);
                put(i, alpha * W2 * sh1[nc]);
#pragma unroll
                for (int m = 0; m < 3; ++m) {
                    float v = (m == nc) ? alpha * W3 : 0.0f;
                    if (t == 13 && m == nc) v += 0.25f * Wsc1[i * 16 + o];
                    put(16 + 3 * i + m, v);
                }
            }
        }
    } else {
        const int bid2 = blockIdx.x - 27;
        if (bid2 == 0) {
            u32x4 z = {0u, 0u, 0u, 0u};
            *reinterpret_cast<u32x4*>(zp + tid * 4) = z;   // 4KB zero page
        }
        const size_t base = ((size_t)bid2 * 256 + tid) * 8;
        const float4* s = reinterpret_cast<const float4*>(x + base);
        float4 v0 = s[0], v1 = s[1];
        u32x4 p;
        p[0] = pack_bf(v0.x, v0.y); p[1] = pack_bf(v0.z, v0.w);
        p[2] = pack_bf(v1.x, v1.y); p[3] = pack_bf(v1.z, v1.w);
        *reinterpret_cast<u32x4*>(xb + base) = p;
    }
}

// ---------------------------------------------------------------------------
// v6: block = (b, X, 8y), 512 thr / 8 waves (2 waves/SIMD -> issue overlap).
// Wave (yh 0..3, nh 0..1): M = 2y x 32z = 64, N = 32 ch.
// Plane-phased staging: x-planes staged as 3 groups; dx=0 taps start after
// draining only plane0 (counted vmcnt), planes 1,2 arrive under compute.
// Raw s_barrier (NOT __syncthreads -> would emit vmcnt(0)).
// ---------------------------------------------------------------------------
#define PLS 384                 // rows per plane (340 real + pad)
#define LDSB (3 * 48 * 1024)    // 147456 B

#define ISSUE_B(s, t) \
  { const char* _p = bTr + (t) * 8192; \
    asm volatile("global_load_dwordx4 %0, %4, off\n\t" \
                 "global_load_dwordx4 %1, %4, off offset:1024\n\t" \
                 "global_load_dwordx4 %2, %4, off offset:2048\n\t" \
                 "global_load_dwordx4 %3, %4, off offset:3072" \
                 : "=&v"(B##s##0), "=&v"(B##s##1), "=&v"(B##s##2), "=&v"(B##s##3) \
                 : "v"(_p)); }

#define LOADA2(s, i0, i1, RCC) { \
  const int _r  = rbase + (RCC); \
  const int _o0 = _r * 128 + ((kg ^ (_r & 7)) << 4); \
  A##s##_##i0 = *reinterpret_cast<const bf16x8*>(abase + _o0); \
  A##s##_##i1 = *reinterpret_cast<const bf16x8*>(abase + (_o0 ^ 64)); }

// row: plane*384 + (dy + y')*34 + dz + mt*16 ; y' = yh*2+yy, z = mt*16+l15
#define RCC6(T, YY, MT) (((T)/9)*PLS + ((((T)/3)%3) + (YY))*34 + ((T)%3) + (MT)*16)

#define LOAD_A8(s, T) \
  LOADA2(s, 0, 1, RCC6(T,0,0)) \
  LOADA2(s, 2, 3, RCC6(T,0,1)) \
  LOADA2(s, 4, 5, RCC6(T,1,0)) \
  LOADA2(s, 6, 7, RCC6(T,1,1))

#define WAITV(N) \
  asm volatile("s_waitcnt vmcnt(" #N ")" ::: "memory"); \
  __builtin_amdgcn_sched_barrier(0);

#define BARRIER() \
  asm volatile("s_barrier" ::: "memory"); \
  __builtin_amdgcn_sched_barrier(0);

#define BC(x) __builtin_bit_cast(bf16x8, x)
#define MF(b_, a_, c_) __builtin_amdgcn_mfma_f32_16x16x32_bf16(BC(b_), a_, c_, 0, 0, 0)

// acc{yy}{mt}{nt}; B: s0=nt0kb0 s1=nt0kb1 s2=nt1kb0 s3=nt1kb1; A idx=yy*4+mt*2+kb
#define MFMA16(bs, as) \
  acc000 = MF(B##bs##0, A##as##_0, acc000); acc001 = MF(B##bs##2, A##as##_0, acc001); \
  acc010 = MF(B##bs##0, A##as##_2, acc010); acc011 = MF(B##bs##2, A##as##_2, acc011); \
  acc100 = MF(B##bs##0, A##as##_4, acc100); acc101 = MF(B##bs##2, A##as##_4, acc101); \
  acc110 = MF(B##bs##0, A##as##_6, acc110); acc111 = MF(B##bs##2, A##as##_6, acc111); \
  acc000 = MF(B##bs##1, A##as##_1, acc000); acc001 = MF(B##bs##3, A##as##_1, acc001); \
  acc010 = MF(B##bs##1, A##as##_3, acc010); acc011 = MF(B##bs##3, A##as##_3, acc011); \
  acc100 = MF(B##bs##1, A##as##_5, acc100); acc101 = MF(B##bs##3, A##as##_5, acc101); \
  acc110 = MF(B##bs##1, A##as##_7, acc110); acc111 = MF(B##bs##3, A##as##_7, acc111);

__global__ __launch_bounds__(512, 2) void conv_mfma6(
    const u16* __restrict__ xb, const u32* __restrict__ zp,
    float* __restrict__ out)
{
    extern __shared__ u16 xt[];   // LDSB bytes

    const int bid0 = blockIdx.x;
    const int bid  = (bid0 & 7) * 64 + (bid0 >> 3);    // XCD-contiguous panels
    const int b    = bid >> 7;
    const int X    = (bid >> 2) & 31;
    const int y0   = (bid & 3) << 3;
    const int tid  = threadIdx.x;
    const int wv   = tid >> 6;       // 0..7
    const int lane = tid & 63;
    const int l15  = lane & 15;
    const int kg   = lane >> 4;
    const int yh   = wv >> 1;        // 0..3
    const int nh   = wv & 1;

    const char* bTr = (const char*)g_kTr + nh * 4096 + lane * 16;

    u32x4 B00, B01, B02, B03, B10, B11, B12, B13, B20, B21, B22, B23,
          B30, B31, B32, B33, B40, B41, B42, B43;
    bf16x8 A0_0, A0_1, A0_2, A0_3, A0_4, A0_5, A0_6, A0_7;
    bf16x8 A1_0, A1_1, A1_2, A1_3, A1_4, A1_5, A1_6, A1_7;

    // ---- prologue B: ALL phase-0 taps (so B waits never force staging drain)
    ISSUE_B(0, 1)    // ops 1-4
    ISSUE_B(1, 3)    // 5-8
    ISSUE_B(2, 4)    // 9-12
    ISSUE_B(3, 5)    // 13-16
    ISSUE_B(4, 7)    // 17-20

    // ---- staging: 3 planes x 48 chunks (43 real), 6 chunks/plane/wave ----
    {
        const int rloc = lane >> 3;
        const int swz  = (lane & 7) ^ rloc;
#pragma unroll
        for (int p = 0; p < 3; ++p) {        // ops 21-26 / 27-32 / 33-38
#pragma unroll
            for (int j = 0; j < 6; ++j) {
                const int cip = wv * 6 + j;          // 0..47 within plane
                const int c   = p * 48 + cip;
                const int rip = cip * 8 + rloc;      // row in plane
                const int yi  = rip / 34;
                const int zid = rip - yi * 34;
                const int xin = X + p - 1;
                const int yin = y0 + yi - 1;
                const int zin = zid - 1;
                const bool inb = (rip < 340) & ((unsigned)xin < 32u)
                               & ((unsigned)yin < 32u) & ((unsigned)zin < 32u);
                const u16* src = inb
                    ? xb + ((size_t)(((b * 32 + xin) * 32 + yin) * 32 + zin) * 64 + swz * 8)
                    : (const u16*)zp;
                __builtin_amdgcn_global_load_lds((const AS1 u32*)src,
                                                 (AS3 u32*)&xt[c * 512], 16, 0, 0);
            }
        }
    }

    const char* abase = reinterpret_cast<const char*>(xt);
    const int rbase = yh * 68 + l15;

    const f32x4 z4 = {0.f, 0.f, 0.f, 0.f};
    f32x4 acc000 = z4, acc001 = z4, acc010 = z4, acc011 = z4;
    f32x4 acc100 = z4, acc101 = z4, acc110 = z4, acc111 = z4;

    // ---- phase 0 (dx=0 taps: 1,3,4,5,7): wait B + plane0 only ----
    WAITV(12)        // drains B(t1..t7) + staging-p0; p1,p2 stay in flight
    BARRIER()
    LOAD_A8(0, 1)
    LOAD_A8(1, 3)   MFMA16(0, 0)    // t=1
    LOAD_A8(0, 4)   MFMA16(1, 1)    // t=3
    LOAD_A8(1, 5)   MFMA16(2, 0)    // t=4
    LOAD_A8(0, 7)   MFMA16(3, 1)    // t=5
                    MFMA16(4, 0)    // t=7

    // ---- phase 1/2 (dx=1: 9..17; dx=2: 19..25): 3-slot dist-2 rotation ----
    ISSUE_B(0, 9)    // ops 39-42
    ISSUE_B(1, 10)   // 43-46
    WAITV(4)         // drains remaining staging + B(t9)
    BARRIER()
    LOAD_A8(1, 9)
    ISSUE_B(2, 11)  LOAD_A8(0, 10)            MFMA16(0, 1)   // t=9
    ISSUE_B(0, 12)  LOAD_A8(1, 11)  WAITV(8)  MFMA16(1, 0)   // t=10
    ISSUE_B(1, 13)  LOAD_A8(0, 12)  WAITV(8)  MFMA16(2, 1)   // t=11
    ISSUE_B(2, 14)  LOAD_A8(1, 13)  WAITV(8)  MFMA16(0, 0)   // t=12
    ISSUE_B(0, 15)  LOAD_A8(0, 14)  WAITV(8)  MFMA16(1, 1)   // t=13
    ISSUE_B(1, 16)  LOAD_A8(1, 15)  WAITV(8)  MFMA16(2, 0)   // t=14
    ISSUE_B(2, 17)  LOAD_A8(0, 16)  WAITV(8)  MFMA16(0, 1)   // t=15
    ISSUE_B(0, 19)  LOAD_A8(1, 17)  WAITV(8)  MFMA16(1, 0)   // t=16
    ISSUE_B(1, 21)  LOAD_A8(0, 19)  WAITV(8)  MFMA16(2, 1)   // t=17
    ISSUE_B(2, 22)  LOAD_A8(1, 21)  WAITV(8)  MFMA16(0, 0)   // t=19
    ISSUE_B(0, 23)  LOAD_A8(0, 22)  WAITV(8)  MFMA16(1, 1)   // t=21
    ISSUE_B(1, 25)  LOAD_A8(1, 23)  WAITV(8)  MFMA16(2, 0)   // t=22
                    LOAD_A8(0, 25)  WAITV(4)  MFMA16(0, 1)   // t=23
                                    WAITV(0)  MFMA16(1, 0)   // t=25

    // ---- epilogue: y = y0+yh*2+yy, z = mt*16+l15, ch = nh*32+nt*16+kg*4 ----
    float* obase = out + (((size_t)(b * 32 + X) * 32 + (y0 + yh * 2)) * 32) * 64
                 + nh * 32 + kg * 4;
    *reinterpret_cast<f32x4*>(obase + l15 * 64)                    = acc000;
    *reinterpret_cast<f32x4*>(obase + l15 * 64 + 16)               = acc001;
    *reinterpret_cast<f32x4*>(obase + (16 + l15) * 64)             = acc010;
    *reinterpret_cast<f32x4*>(obase + (16 + l15) * 64 + 16)        = acc011;
    *reinterpret_cast<f32x4*>(obase + 2048 + l15 * 64)             = acc100;
    *reinterpret_cast<f32x4*>(obase + 2048 + l15 * 64 + 16)        = acc101;
    *reinterpret_cast<f32x4*>(obase + 2048 + (16 + l15) * 64)      = acc110;
    *reinterpret_cast<f32x4*>(obase + 2048 + (16 + l15) * 64 + 16) = acc111;
}

// ---------------------------------------------------------------------------
// Fallback (fp32 staging through VGPRs, old g_kT layout), if ws too small.
// ---------------------------------------------------------------------------
#define ZS 68
#define NROWS 408

__global__ __launch_bounds__(256, 2) void conv_mfma_fb(
    const float* __restrict__ x, float* __restrict__ out)
{
    __shared__ __align__(16) u16 xts[NROWS * ZS];
    const int bid0 = blockIdx.x;
    const int bid  = (bid0 & 7) * 256 + (bid0 >> 3);
    const int b   = bid >> 9;
    const int X   = (bid >> 4) & 31;
    const int y0  = (bid & 15) << 1;
    const int tid = threadIdx.x;

    {
        const int pr = tid >> 2;
        const int q  = tid & 3;
#pragma unroll
        for (int pass = 0; pass < 7; ++pass) {
            const int idx = pass * 64 + pr;
            if (idx < NROWS) {
                const int rid = idx / 34;
                const int zid = idx - rid * 34;
                const int xin = X + (rid >> 2) - 1;
                const int yin = y0 + (rid & 3) - 1;
                const int zin = zid - 1;
                u32x4 p0 = {0u,0u,0u,0u}, p1 = {0u,0u,0u,0u};
                if ((unsigned)xin < 32u && (unsigned)yin < 32u && (unsigned)zin < 32u) {
                    const float4* src = reinterpret_cast<const float4*>(
                        x + ((((b * 32 + xin) * 32 + yin) * 32 + zin) * 64 + q * 16));
                    float4 v0 = src[0], v1 = src[1], v2 = src[2], v3 = src[3];
                    p0[0] = pack_bf(v0.x, v0.y); p0[1] = pack_bf(v0.z, v0.w);
                    p0[2] = pack_bf(v1.x, v1.y); p0[3] = pack_bf(v1.z, v1.w);
                    p1[0] = pack_bf(v2.x, v2.y); p1[1] = pack_bf(v2.z, v2.w);
                    p1[2] = pack_bf(v3.x, v3.y); p1[3] = pack_bf(v3.z, v3.w);
                }
                u16* dst = &xts[idx * ZS + q * 16];
                *reinterpret_cast<u32x4*>(dst)     = p0;
                *reinterpret_cast<u32x4*>(dst + 8) = p1;
            }
        }
    }
    __syncthreads();

    const int w    = tid >> 6;
    const int lane = tid & 63;
    const int l15  = lane & 15;
    const int kg   = lane >> 4;
    const int mh   = w >> 1;
    const int nh   = w & 1;
    const int chb  = kg * 8;

    const u16* abase = &xts[l15 * ZS + chb];
    const u16* bbase = &g_kT[(nh * 32 + l15) * 64 + chb];

    const f32x4 z4 = {0.f, 0.f, 0.f, 0.f};
    f32x4 acc[2][2] = {{z4, z4}, {z4, z4}};

    constexpr int NT = 19;
    constexpr int TAPS[NT] = {1,3,4,5,7,9,10,11,12,13,14,15,16,17,19,21,22,23,25};

#pragma unroll
    for (int ti = 0; ti < NT; ++ti) {
        const int t = TAPS[ti];
        const int dxt = t / 9, dyt = (t / 3) % 3, dzt = t % 3;
        const int rid = dxt * 4 + mh + dyt;
        bf16x8 bfr[4], afr[4];
#pragma unroll
        for (int kb = 0; kb < 2; ++kb)
#pragma unroll
        for (int nt = 0; nt < 2; ++nt)
            bfr[kb*2+nt] = *reinterpret_cast<const bf16x8*>(
                bbase + (t * 64 + nt * 16) * 64 + kb * 32);
#pragma unroll
        for (int kb = 0; kb < 2; ++kb)
#pragma unroll
        for (int mt = 0; mt < 2; ++mt)
            afr[kb*2+mt] = *reinterpret_cast<const bf16x8*>(
                abase + (rid * 34 + dzt + mt * 16) * ZS + kb * 32);
#pragma unroll
        for (int kb = 0; kb < 2; ++kb)
#pragma unroll
        for (int mt = 0; mt < 2; ++mt)
#pragma unroll
        for (int nt = 0; nt < 2; ++nt)
            acc[mt][nt] = __builtin_amdgcn_mfma_f32_16x16x32_bf16(
                bfr[kb*2+nt], afr[kb*2+mt], acc[mt][nt], 0, 0, 0);
    }

    float* obase = out + (((b * 32 + X) * 32 + (y0 + mh)) * 32) * 64 + nh * 32 + kg * 4;
#pragma unroll
    for (int mt = 0; mt < 2; ++mt)
#pragma unroll
        for (int nt = 0; nt < 2; ++nt) {
            float4 v;
            v.x = acc[mt][nt][0]; v.y = acc[mt][nt][1];
            v.z = acc[mt][nt][2]; v.w = acc[mt][nt][3];
            *reinterpret_cast<float4*>(obase + (mt * 16 + l15) * 64 + nt * 16) = v;
        }
}

extern "C" void kernel_launch(void* const* d_in, const int* in_sizes, int n_in,
                              void* d_out, int out_size, void* d_ws, size_t ws_size,
                              hipStream_t stream)
{
    const float* x    = (const float*)d_in[0];
    const float* Wsc0 = (const float*)d_in[1];
    const float* Wsc1 = (const float*)d_in[2];
    const float* w1   = (const float*)d_in[3];
    const float* w2   = (const float*)d_in[4];
    const float* w3   = (const float*)d_in[5];
    const float* w4   = (const float*)d_in[6];
    float* out = (float*)d_out;

    const size_t xb_bytes = (size_t)4 * 32 * 32 * 32 * 64 * 2;   // 16.8 MB
    if (ws_size >= 4096 + xb_bytes) {
        u32* zp = (u32*)d_ws;
        u16* xb = (u16*)((char*)d_ws + 4096);
        prep<<<dim3(27 + 4096), dim3(256), 0, stream>>>(Wsc0, Wsc1, w1, w2, w3, w4,
                                                        x, xb, zp);
        conv_mfma6<<<dim3(512), dim3(512), LDSB, stream>>>(xb, zp, out);
    } else {
        prep<<<dim3(27), dim3(256), 0, stream>>>(Wsc0, Wsc1, w1, w2, w3, w4,
                                                 x, (u16*)nullptr, (u32*)nullptr);
        conv_mfma_fb<<<dim3(2048), dim3(256), 0, stream>>>(x, out);
    }
}